// Round 1
// baseline (63.557 us; speedup 1.0000x reference)
//
#include <hip/hip_runtime.h>

#define TILE 16

__device__ __forceinline__ float silu_f(float x) {
    return x / (1.0f + __expf(-x));
}

// Uniform-knot cubic B-spline: T=(x-g0)*invh, m=floor(T) clamped to [0,TMAX-1].
// Writes the 4 nonzero basis values (zeroed when T outside [0,TMAX)), which
// correspond to padded-coefficient indices m, m+1, m+2, m+3 (pad offset +3).
template <int TMAX>
__device__ __forceinline__ int bspl(float x, float g0, float invh, float N[4]) {
    float T = (x - g0) * invh;
    float mf = floorf(T);
    bool inb = (T >= 0.0f) && (T < (float)TMAX);
    mf = fminf(fmaxf(mf, 0.0f), (float)(TMAX - 1));
    float w = T - mf;
    float w2 = w * w;
    float w3 = w2 * w;
    float om = 1.0f - w;
    float sc = inb ? (1.0f / 6.0f) : 0.0f;
    N[0] = om * om * om * sc;
    N[1] = (3.0f * w3 - 6.0f * w2 + 4.0f) * sc;
    N[2] = (-3.0f * w3 + 3.0f * w2 + 3.0f * w + 1.0f) * sc;
    N[3] = w3 * sc;
    return (int)mf;
}

__global__ __launch_bounds__(256) void ZS_MKAN_72121090834671_kernel(
    const float* __restrict__ x,
    const float* __restrict__ base_w1, const float* __restrict__ spline_w1,
    const float* __restrict__ scaler1,
    const float* __restrict__ base_w2, const float* __restrict__ spline_w2,
    const float* __restrict__ scaler2,
    const float* __restrict__ conv_w, const float* __restrict__ conv_b,
    const float* __restrict__ base_w6, const float* __restrict__ spline_w6,
    const float* __restrict__ scaler6,
    float* __restrict__ out)
{
    __shared__ float sx[3][20][20];      // x tile + halo2
    __shared__ float sy[6][18][18];      // layer1 out, tile + halo1
    __shared__ float sbw1[18];           // base_w1 [k*9+s]
    __shared__ float ssw1[2][9][12];     // spline_w1*scaler1, padded +3 each side
    __shared__ float sbw2[18];
    __shared__ float ssw2[2][9][12];
    __shared__ float scw[36];            // conv_w [o*12+c]
    __shared__ float scb[3];
    __shared__ float sw6[14];            // spline_w6*scaler6, padded (8 coefs)
    __shared__ float sb6;

    const int tid = threadIdx.x;
    const int tx0 = blockIdx.x * TILE;
    const int ty0 = blockIdx.y * TILE;
    const int b   = blockIdx.z;

    // ---- weight preload (padded; pre-multiplied by scaler) ----
    for (int i = tid; i < 216; i += 256) {
        int k = i / 108, r = i % 108, s = r / 12, p = r % 12, c = p - 3;
        float v1 = 0.0f, v2 = 0.0f;
        if (c >= 0 && c < 6) {
            v1 = spline_w1[(k * 9 + s) * 6 + c] * scaler1[k * 9 + s];
            v2 = spline_w2[(k * 9 + s) * 6 + c] * scaler2[k * 9 + s];
        }
        ssw1[k][s][p] = v1;
        ssw2[k][s][p] = v2;
    }
    if (tid < 18) { sbw1[tid] = base_w1[tid]; sbw2[tid] = base_w2[tid]; }
    if (tid < 36) scw[tid] = conv_w[tid];
    if (tid < 3)  scb[tid] = conv_b[tid];
    if (tid < 14) {
        int c = tid - 3;
        sw6[tid] = (c >= 0 && c < 8) ? spline_w6[c] * scaler6[0] : 0.0f;
    }
    if (tid == 0) sb6 = base_w6[0];

    // ---- stage 0: load x tile + halo2 (zero-padded) ----
    for (int i = tid; i < 3 * 20 * 20; i += 256) {
        int c = i / 400, r = i % 400, ly = r / 20, lx = r % 20;
        int gy = ty0 - 2 + ly, gx = tx0 - 2 + lx;
        float v = 0.0f;
        if (gy >= 0 && gy < 256 && gx >= 0 && gx < 256)
            v = x[((b * 3 + c) * 256 + gy) * 256 + gx];
        sx[c][ly][lx] = v;
    }
    __syncthreads();

    // ---- stage 1: KAN layer1 (3ch -> 6ch) on 18x18 region (origin -1) ----
    for (int i = tid; i < 3 * 18 * 18; i += 256) {
        int c = i / 324, r = i % 324, ly = r / 18, lx = r % 18;
        float a0 = 0.0f, a1 = 0.0f;
        #pragma unroll
        for (int s = 0; s < 9; ++s) {
            int dy = s / 3, dx = s % 3;
            float xv = sx[c][ly + dy][lx + dx];
            float sl = silu_f(xv);
            float N[4];
            int m = bspl<9>(xv, -3.0f, 1.5f, N);
            float sp0 = N[0] * ssw1[0][s][m]     + N[1] * ssw1[0][s][m + 1]
                      + N[2] * ssw1[0][s][m + 2] + N[3] * ssw1[0][s][m + 3];
            float sp1 = N[0] * ssw1[1][s][m]     + N[1] * ssw1[1][s][m + 1]
                      + N[2] * ssw1[1][s][m + 2] + N[3] * ssw1[1][s][m + 3];
            a0 += sl * sbw1[s]     + sp0;
            a1 += sl * sbw1[9 + s] + sp1;
        }
        int gy = ty0 - 1 + ly, gx = tx0 - 1 + lx;
        bool inimg = (gy >= 0 && gy < 256 && gx >= 0 && gx < 256);
        sy[c * 2 + 0][ly][lx] = inimg ? a0 : 0.0f;   // layer2 sees ZERO pad, not f(0)
        sy[c * 2 + 1][ly][lx] = inimg ? a1 : 0.0f;
    }
    __syncthreads();

    // ---- stage 2: KAN layer2 (6->12) + 1x1 conv (12->3) + KAN layer6 ----
    const int ly = tid / 16, lx = tid % 16;
    float z[12];
    #pragma unroll
    for (int c = 0; c < 6; ++c) {
        float a0 = 0.0f, a1 = 0.0f;
        #pragma unroll
        for (int s = 0; s < 9; ++s) {
            int dy = s / 3, dx = s % 3;
            float yv = sy[c][ly + dy][lx + dx];
            float sl = silu_f(yv);
            float N[4];
            int m = bspl<9>(yv, -3.0f, 1.5f, N);
            float sp0 = N[0] * ssw2[0][s][m]     + N[1] * ssw2[0][s][m + 1]
                      + N[2] * ssw2[0][s][m + 2] + N[3] * ssw2[0][s][m + 3];
            float sp1 = N[0] * ssw2[1][s][m]     + N[1] * ssw2[1][s][m + 1]
                      + N[2] * ssw2[1][s][m + 2] + N[3] * ssw2[1][s][m + 3];
            a0 += sl * sbw2[s]     + sp0;
            a1 += sl * sbw2[9 + s] + sp1;
        }
        z[c * 2]     = a0;
        z[c * 2 + 1] = a1;
    }
    const int gy = ty0 + ly, gx = tx0 + lx;
    #pragma unroll
    for (int o = 0; o < 3; ++o) {
        float v = scb[o];
        #pragma unroll
        for (int c = 0; c < 12; ++c) v += scw[o * 12 + c] * z[c];
        float sl = silu_f(v);
        float N[4];
        int m = bspl<11>(v, -2.2f, 2.5f, N);
        float sp = N[0] * sw6[m]     + N[1] * sw6[m + 1]
                 + N[2] * sw6[m + 2] + N[3] * sw6[m + 3];
        out[((b * 3 + o) * 256 + gy) * 256 + gx] = sl * sb6 + sp;
    }
}

extern "C" void kernel_launch(void* const* d_in, const int* in_sizes, int n_in,
                              void* d_out, int out_size, void* d_ws, size_t ws_size,
                              hipStream_t stream) {
    (void)in_sizes; (void)n_in; (void)d_ws; (void)ws_size; (void)out_size;
    const float* x         = (const float*)d_in[0];
    const float* base_w1   = (const float*)d_in[1];
    const float* spline_w1 = (const float*)d_in[2];
    const float* scaler1   = (const float*)d_in[3];
    const float* base_w2   = (const float*)d_in[4];
    const float* spline_w2 = (const float*)d_in[5];
    const float* scaler2   = (const float*)d_in[6];
    const float* conv_w    = (const float*)d_in[7];
    const float* conv_b    = (const float*)d_in[8];
    const float* base_w6   = (const float*)d_in[9];
    const float* spline_w6 = (const float*)d_in[10];
    const float* scaler6   = (const float*)d_in[11];
    float* out = (float*)d_out;

    dim3 grid(256 / TILE, 256 / TILE, 4);
    dim3 block(256);
    ZS_MKAN_72121090834671_kernel<<<grid, block, 0, stream>>>(
        x, base_w1, spline_w1, scaler1, base_w2, spline_w2, scaler2,
        conv_w, conv_b, base_w6, spline_w6, scaler6, out);
}